// Round 1
// baseline (210.014 us; speedup 1.0000x reference)
//
#include <hip/hip_runtime.h>
#include <math.h>

#define BB 4
#define CC 192
#define HH 56
#define WW 56
#define HWW 3136
#define NSH 14
#define NSW 13
#define NS 27
#define CST 193   // LDS row stride: 193 % 32 == 1 -> conflict-free across h

__device__ __forceinline__ float fast_tanh(float a) {
    // tanh(a) = 1 - 2/(exp(2a)+1); saturates correctly at +/-inf
    float e = __expf(2.0f * a);
    return 1.0f - __fdividef(2.0f, e + 1.0f);
}

// ---------------------------------------------------------------------------
// Kernel 1: transpose x (B,C,H,W) -> xt (B,H*W,C)
// ---------------------------------------------------------------------------
__global__ __launch_bounds__(256) void k_transpose(const float* __restrict__ x,
                                                   float* __restrict__ xt) {
    __shared__ float tile[32][33];
    int bx = blockIdx.x;           // pixel tile (98)
    int by = blockIdx.y;           // channel tile (6)
    int b  = blockIdx.z;
    int tx = threadIdx.x;          // 32
    int ty = threadIdx.y;          // 8
    int p0 = bx * 32, c0 = by * 32;
#pragma unroll
    for (int i = 0; i < 4; i++) {
        int c = c0 + ty + 8 * i;
        tile[ty + 8 * i][tx] = x[(b * CC + c) * HWW + p0 + tx];
    }
    __syncthreads();
#pragma unroll
    for (int i = 0; i < 4; i++) {
        int p = p0 + ty + 8 * i;
        xt[(b * HWW + p) * CC + c0 + tx] = tile[tx][ty + 8 * i];
    }
}

// ---------------------------------------------------------------------------
// Kernel 2: scores. Blocks [0, B*W): column blocks (H-shifts, i=0..13)
//           Blocks [B*W, B*W+B*H): row blocks (W-shifts, i=14..26)
// scores layout: (B, 27, H, W) f32
// ---------------------------------------------------------------------------
__global__ __launch_bounds__(256) void k_scores(const float* __restrict__ xt,
                                                float* __restrict__ scores) {
    __shared__ float Xs[HH * CST];
    const float scl = 0.19245008972987526f;  // 1/sqrt(27)
    int bid = blockIdx.x;
    int tid = threadIdx.x;

    if (bid < BB * WW) {
        int b = bid / WW, w = bid % WW;
        for (int idx = tid; idx < HH * CC; idx += 256) {
            int h = idx / CC, c = idx % CC;
            Xs[h * CST + c] = xt[(b * HWW + h * WW + w) * CC + c];
        }
        __syncthreads();
        for (int item = tid; item < NSH * HH; item += 256) {
            int i = item / HH, h = item % HH;
            int h2 = h - 4 * i; if (h2 < 0) h2 += HH;
            const float* r1 = &Xs[h * CST];
            const float* r2 = &Xs[h2 * CST];
            float s = 0.f;
#pragma unroll 4
            for (int c = 0; c < CC; c++) s += fast_tanh(r1[c] * r2[c] * scl);
            scores[(b * NS + i) * HWW + h * WW + w] = s;
        }
    } else {
        int rid = bid - BB * WW;
        int b = rid / HH, h = rid % HH;
        for (int idx = tid; idx < WW * CC; idx += 256) {
            int w = idx / CC, c = idx % CC;
            Xs[w * CST + c] = xt[(b * HWW + h * WW + w) * CC + c];
        }
        __syncthreads();
        for (int item = tid; item < NSW * WW; item += 256) {
            int j = item / WW, w = item % WW;
            int w2 = w - 4 * (j + 1); if (w2 < 0) w2 += WW;
            const float* r1 = &Xs[w * CST];
            const float* r2 = &Xs[w2 * CST];
            float s = 0.f;
#pragma unroll 4
            for (int c = 0; c < CC; c++) s += fast_tanh(r1[c] * r2[c] * scl);
            scores[(b * NS + NSH + j) * HWW + h * WW + w] = s;
        }
    }
}

// ---------------------------------------------------------------------------
// Kernel 3: accH — per-column softmax weights + H-shift weighted sum.
// Writes out_t (B,H*W,C) (initializes it).
// ---------------------------------------------------------------------------
__global__ __launch_bounds__(256) void k_accH(const float* __restrict__ xt,
                                              const float* __restrict__ scores,
                                              float* __restrict__ outt) {
    __shared__ float Xs[HH * CST];
    __shared__ float Wt[NSH][HH];
    int b = blockIdx.x / WW, w = blockIdx.x % WW;
    int tid = threadIdx.x;
    for (int idx = tid; idx < HH * CC; idx += 256) {
        int h = idx / CC, c = idx % CC;
        Xs[h * CST + c] = xt[(b * HWW + h * WW + w) * CC + c];
    }
    if (tid < HH) {
        int h = tid;
        float sc[NS];
        float mx = -1e30f;
        for (int i = 0; i < NS; i++) {
            sc[i] = scores[(b * NS + i) * HWW + h * WW + w];
            mx = fmaxf(mx, sc[i]);
        }
        float sum = 0.f;
        for (int i = 0; i < NS; i++) { sc[i] = __expf(sc[i] - mx); sum += sc[i]; }
        float inv = __fdividef(1.f, sum);
        for (int i = 0; i < NSH; i++) Wt[i][h] = sc[i] * inv;
    }
    __syncthreads();
    for (int idx = tid; idx < HH * CC; idx += 256) {
        int h = idx / CC, c = idx % CC;
        float acc = 0.f;
#pragma unroll
        for (int i = 0; i < NSH; i++) {
            int h2 = h - 4 * i; if (h2 < 0) h2 += HH;
            acc += Wt[i][h] * Xs[h2 * CST + c];
        }
        outt[(b * HWW + h * WW + w) * CC + c] = acc;
    }
}

// ---------------------------------------------------------------------------
// Kernel 4: accW — per-row softmax weights + W-shift weighted sum (adds).
// ---------------------------------------------------------------------------
__global__ __launch_bounds__(256) void k_accW(const float* __restrict__ xt,
                                              const float* __restrict__ scores,
                                              float* __restrict__ outt) {
    __shared__ float Xs[WW * CST];
    __shared__ float Wt[NSW][WW];
    int b = blockIdx.x / HH, h = blockIdx.x % HH;
    int tid = threadIdx.x;
    for (int idx = tid; idx < WW * CC; idx += 256) {
        int w = idx / CC, c = idx % CC;
        Xs[w * CST + c] = xt[(b * HWW + h * WW + w) * CC + c];
    }
    if (tid < WW) {
        int w = tid;
        float sc[NS];
        float mx = -1e30f;
        for (int i = 0; i < NS; i++) {
            sc[i] = scores[(b * NS + i) * HWW + h * WW + w];
            mx = fmaxf(mx, sc[i]);
        }
        float sum = 0.f;
        for (int i = 0; i < NS; i++) { sc[i] = __expf(sc[i] - mx); sum += sc[i]; }
        float inv = __fdividef(1.f, sum);
        for (int j = 0; j < NSW; j++) Wt[j][w] = sc[NSH + j] * inv;
    }
    __syncthreads();
    for (int idx = tid; idx < WW * CC; idx += 256) {
        int w = idx / CC, c = idx % CC;
        int pos = (b * HWW + h * WW + w) * CC + c;
        float acc = outt[pos];
#pragma unroll
        for (int j = 0; j < NSW; j++) {
            int w2 = w - 4 * (j + 1); if (w2 < 0) w2 += WW;
            acc += Wt[j][w] * Xs[w2 * CST + c];
        }
        outt[pos] = acc;
    }
}

// ---------------------------------------------------------------------------
// Kernel 5: 1x1 conv GEMM (M=12544 pixels, N=192 out-ch, K=384) + bias + BN
//           + exact GELU, output in (B,C,H,W).
// Tile: 64(M) x 64(N), K-chunk 32, 4x4 per-thread microtile, f32 vector ALU.
// ---------------------------------------------------------------------------
__global__ __launch_bounds__(256) void k_conv(const float* __restrict__ xt,
                                              const float* __restrict__ outt,
                                              const float* __restrict__ cw,
                                              const float* __restrict__ cb,
                                              const float* __restrict__ gma,
                                              const float* __restrict__ bta,
                                              const float* __restrict__ mea,
                                              const float* __restrict__ var,
                                              float* __restrict__ y) {
    __shared__ float As[32][68];
    __shared__ float Bs[32][68];
    int bm = blockIdx.x * 64;   // 196 tiles; 3136 % 64 == 0 so tile stays in one batch
    int bn = blockIdx.y * 64;   // 3 tiles
    int tid = threadIdx.x;
    int tx = tid % 16, ty = tid / 16;
    float acc[4][4] = {};
    for (int kc = 0; kc < 384; kc += 32) {
        const float* srcA = (kc < CC) ? (xt + kc) : (outt + kc - CC);
        int q = tid % 8;   // k-quad
        int m = tid / 8;   // 0..31
#pragma unroll
        for (int r = 0; r < 2; r++) {
            int mm = m + 32 * r;
            float4 v = *(const float4*)&srcA[(bm + mm) * CC + q * 4];
            As[q * 4 + 0][mm] = v.x; As[q * 4 + 1][mm] = v.y;
            As[q * 4 + 2][mm] = v.z; As[q * 4 + 3][mm] = v.w;
        }
#pragma unroll
        for (int r = 0; r < 2; r++) {
            int oo = m + 32 * r;
            float4 v = *(const float4*)&cw[(bn + oo) * 384 + kc + q * 4];
            Bs[q * 4 + 0][oo] = v.x; Bs[q * 4 + 1][oo] = v.y;
            Bs[q * 4 + 2][oo] = v.z; Bs[q * 4 + 3][oo] = v.w;
        }
        __syncthreads();
#pragma unroll
        for (int kk = 0; kk < 32; kk++) {
            float4 a  = *(const float4*)&As[kk][ty * 4];
            float4 bv = *(const float4*)&Bs[kk][tx * 4];
            float av[4] = {a.x, a.y, a.z, a.w};
            float bb[4] = {bv.x, bv.y, bv.z, bv.w};
#pragma unroll
            for (int i = 0; i < 4; i++)
#pragma unroll
                for (int j = 0; j < 4; j++) acc[i][j] += av[i] * bb[j];
        }
        __syncthreads();
    }
    int b = bm / HWW;
    int p0 = bm % HWW;
#pragma unroll
    for (int j = 0; j < 4; j++) {
        int o = bn + tx * 4 + j;
        float bias = cb[o];
        float inv  = gma[o] * rsqrtf(var[o] + 1e-5f);
        float mean = mea[o], beta = bta[o];
        float vals[4];
#pragma unroll
        for (int i = 0; i < 4; i++) {
            float v = acc[i][j] + bias;
            v = (v - mean) * inv + beta;
            v = 0.5f * v * (1.0f + erff(v * 0.70710678118654752f));
            vals[i] = v;
        }
        float4 st; st.x = vals[0]; st.y = vals[1]; st.z = vals[2]; st.w = vals[3];
        *(float4*)&y[(b * CC + o) * HWW + p0 + ty * 4] = st;
    }
}

// ---------------------------------------------------------------------------
extern "C" void kernel_launch(void* const* d_in, const int* in_sizes, int n_in,
                              void* d_out, int out_size, void* d_ws, size_t ws_size,
                              hipStream_t stream) {
    const float* x   = (const float*)d_in[0];
    const float* cw  = (const float*)d_in[1];
    const float* cb  = (const float*)d_in[2];
    const float* gma = (const float*)d_in[3];
    const float* bta = (const float*)d_in[4];
    const float* mea = (const float*)d_in[5];
    const float* var = (const float*)d_in[6];
    float* out = (float*)d_out;

    float* ws     = (float*)d_ws;
    float* xt     = ws;                       // B*HW*C = 2408448 floats
    float* outt   = ws + 2408448;             // B*HW*C
    float* scores = ws + 2 * 2408448;         // B*27*HW = 338688 floats

    k_transpose<<<dim3(98, 6, 4), dim3(32, 8), 0, stream>>>(x, xt);
    k_scores<<<BB * WW + BB * HH, 256, 0, stream>>>(xt, scores);
    k_accH<<<BB * WW, 256, 0, stream>>>(xt, scores, outt);
    k_accW<<<BB * HH, 256, 0, stream>>>(xt, scores, outt);
    k_conv<<<dim3(196, 3), 256, 0, stream>>>(xt, outt, cw, cb, gma, bta, mea, var, out);
}

// Round 5
// 133.082 us; speedup vs baseline: 1.5781x; 1.5781x over previous
//
#include <hip/hip_runtime.h>
#include <hip/hip_bf16.h>
#include <math.h>

#define BB 4
#define CC 192
#define HH 56
#define WW 56
#define HWW 3136

typedef __attribute__((ext_vector_type(8))) short short8;
typedef __attribute__((ext_vector_type(4))) float f32x4;

__device__ __forceinline__ unsigned short f2b(float f) {
    __hip_bfloat16 h = __float2bfloat16(f);
    return __builtin_bit_cast(unsigned short, h);
}
__device__ __forceinline__ float b2f(unsigned short u) {
    unsigned int x = ((unsigned int)u) << 16;
    return __builtin_bit_cast(float, x);
}
__device__ __forceinline__ void fma4(float4& a, float w, const float4& x) {
    a.x += w * x.x; a.y += w * x.y; a.z += w * x.z; a.w += w * x.w;
}

// ---------------------------------------------------------------------------
// Kernel 1: transpose x (B,C,H,W) -> xt (B,H*W,C) f32
// ---------------------------------------------------------------------------
__global__ __launch_bounds__(256) void k_transpose(const float* __restrict__ x,
                                                   float* __restrict__ xt) {
    __shared__ float tile[32][33];
    int bx = blockIdx.x, by = blockIdx.y, b = blockIdx.z;
    int tx = threadIdx.x, ty = threadIdx.y;
    int p0 = bx * 32, c0 = by * 32;
#pragma unroll
    for (int i = 0; i < 4; i++) {
        int c = c0 + ty + 8 * i;
        tile[ty + 8 * i][tx] = x[(b * CC + c) * HWW + p0 + tx];
    }
    __syncthreads();
#pragma unroll
    for (int i = 0; i < 4; i++) {
        int p = p0 + ty + 8 * i;
        xt[(b * HWW + p) * CC + c0 + tx] = tile[tx][ty + 8 * i];
    }
}

// ---------------------------------------------------------------------------
// Kernel 2: conv_w f32 -> split bf16 (hi + residual lo). 73728 elements.
// ---------------------------------------------------------------------------
__global__ __launch_bounds__(256) void k_convw(const float* __restrict__ cw,
                                               unsigned short* __restrict__ cwh,
                                               unsigned short* __restrict__ cwl) {
    int i = blockIdx.x * 256 + threadIdx.x;
    if (i < CC * 2 * CC) {
        float v = cw[i];
        unsigned short hi = f2b(v);
        cwh[i] = hi;
        cwl[i] = f2b(v - b2f(hi));
    }
}

// ---------------------------------------------------------------------------
// Kernel 3: scores with pair symmetry + channel-half split.
// grid: [0,448) H-column blocks, [448,896) W-row blocks.
// (448 = 2 halves x 4 batches x 56 columns/rows)
// sp layout: [half][b][27][3136] partials (f32).
// ---------------------------------------------------------------------------
__global__ __launch_bounds__(256) void k_scores(const float* __restrict__ xt,
                                                float* __restrict__ sp) {
    __shared__ float Xs[56 * 100];   // 56 rows x 96ch (+4 pad), 22.4KB
    int bid = blockIdx.x, tid = threadIdx.x;
    bool isH = bid < 448;
    int lid = isH ? bid : bid - 448;
    int half = lid & 1;
    int cb = lid >> 1;               // 0..223
    int b = cb / 56, l0 = cb % 56;   // column w (H) or row h (W)

    const float* src = xt + (size_t)(b * HWW) * CC + half * 96;
    for (int idx = tid; idx < 56 * 24; idx += 256) {
        int t = idx / 24, cq = idx % 24;
        int pix = isH ? (t * WW + l0) : (l0 * WW + t);
        float4 v = *(const float4*)(src + (size_t)pix * CC + cq * 4);
        *(float4*)&Xs[t * 100 + cq * 4] = v;
    }
    __syncthreads();

    const float K2 = 0.38490017945975050f;  // 2 / sqrt(27)
    int nU = isH ? 420 : 364;               // 4 classes x (105 | 91) pairs
    for (int u = tid; u < nU; u += 256) {
        int r = u & 3, p = u >> 2;
        int a, bb;
        if (isH) {
            a = (int)((sqrtf((float)(8 * p + 1)) - 1.0f) * 0.5f);
            bb = p - (a * (a + 1)) / 2;
        } else {
            int ap = (int)((sqrtf((float)(8 * p + 1)) - 1.0f) * 0.5f);
            bb = p - (ap * (ap + 1)) / 2;
            a = ap + 1;
        }
        const float* pA = &Xs[(r + 4 * a) * 100];
        const float* pB = &Xs[(r + 4 * bb) * 100];
        float s0 = 0.f, s1 = 0.f, s2 = 0.f, s3 = 0.f;
#pragma unroll
        for (int q = 0; q < 24; q++) {
            float4 av = *(const float4*)(pA + q * 4);
            float4 bv = *(const float4*)(pB + q * 4);
            s0 += __builtin_amdgcn_rcpf(__expf(av.x * bv.x * K2) + 1.0f);
            s1 += __builtin_amdgcn_rcpf(__expf(av.y * bv.y * K2) + 1.0f);
            s2 += __builtin_amdgcn_rcpf(__expf(av.z * bv.z * K2) + 1.0f);
            s3 += __builtin_amdgcn_rcpf(__expf(av.w * bv.w * K2) + 1.0f);
        }
        // sum_c tanh = sum_c (1 - 2/(e+1)) = 96 - 2*sum rcp
        float s = 96.0f - 2.0f * (s0 + s1 + s2 + s3);
        int sb = (half * BB + b) * 27;
        if (isH) {
            int i1 = a - bb;
            int h1 = r + 4 * a, h2 = r + 4 * bb;
            sp[(sb + i1) * HWW + h1 * WW + l0] = s;
            if (a != bb) sp[(sb + 14 - i1) * HWW + h2 * WW + l0] = s;
        } else {
            int d = a - bb;                        // 1..13
            int w1 = r + 4 * a, w2 = r + 4 * bb;
            sp[(sb + 14 + (d - 1)) * HWW + l0 * WW + w1] = s;
            sp[(sb + 14 + (13 - d)) * HWW + l0 * WW + w2] = s;
        }
    }
}

// ---------------------------------------------------------------------------
// Kernels 4a/4b: softmax + weighted accumulation, register-blocked per class.
// accH (224 column blocks) writes outt f32; accW (224 row blocks) RMW-adds.
// ---------------------------------------------------------------------------
template <bool IS_H>
__device__ __forceinline__ void acc_body(const float* __restrict__ xt,
                                         const float* __restrict__ sp,
                                         float* __restrict__ outt) {
    __shared__ float Wt[14 * 56];
    int lid = blockIdx.x, tid = threadIdx.x;
    int b = lid / 56, l0 = lid % 56;

    if (tid < 56) {
        int pix = IS_H ? (tid * WW + l0) : (l0 * WW + tid);
        float sc[27], mx = -1e30f;
#pragma unroll
        for (int s = 0; s < 27; s++) {
            float v = sp[((0 * BB + b) * 27 + s) * HWW + pix] +
                      sp[((1 * BB + b) * 27 + s) * HWW + pix];
            sc[s] = v; mx = fmaxf(mx, v);
        }
        float sum = 0.f;
#pragma unroll
        for (int s = 0; s < 27; s++) { sc[s] = __expf(sc[s] - mx); sum += sc[s]; }
        float inv = __builtin_amdgcn_rcpf(sum);
        if (IS_H) {
#pragma unroll
            for (int i = 0; i < 14; i++) Wt[i * 56 + tid] = sc[i] * inv;
        } else {
#pragma unroll
            for (int j = 0; j < 13; j++) Wt[j * 56 + tid] = sc[14 + j] * inv;
        }
    }
    __syncthreads();
    if (tid < 192) {
        int r = tid & 3, q = tid >> 2;     // class, channel-quad
        float4 in[14];
#pragma unroll
        for (int t = 0; t < 14; t++) {
            int pix = IS_H ? ((r + 4 * t) * WW + l0) : (l0 * WW + (r + 4 * t));
            in[t] = *(const float4*)(xt + (size_t)(b * HWW + pix) * CC + q * 4);
        }
        float4 acc[14] = {};
        if (IS_H) {
#pragma unroll
            for (int i = 0; i < 14; i++)
#pragma unroll
                for (int a = 0; a < 14; a++)
                    fma4(acc[a], Wt[i * 56 + (r + 4 * a)], in[(a - i + 14) % 14]);
        } else {
#pragma unroll
            for (int j = 0; j < 13; j++)
#pragma unroll
                for (int a = 0; a < 14; a++)
                    fma4(acc[a], Wt[j * 56 + (r + 4 * a)], in[(a - j - 1 + 14) % 14]);
        }
#pragma unroll
        for (int a = 0; a < 14; a++) {
            int pix = IS_H ? ((r + 4 * a) * WW + l0) : (l0 * WW + (r + 4 * a));
            float* dst = outt + (size_t)(b * HWW + pix) * CC + q * 4;
            if (IS_H) {
                *(float4*)dst = acc[a];
            } else {
                float4 prev = *(const float4*)dst;
                prev.x += acc[a].x; prev.y += acc[a].y;
                prev.z += acc[a].z; prev.w += acc[a].w;
                *(float4*)dst = prev;
            }
        }
    }
}

__global__ __launch_bounds__(256) void k_accH(const float* __restrict__ xt,
                                              const float* __restrict__ sp,
                                              float* __restrict__ outt) {
    acc_body<true>(xt, sp, outt);
}
__global__ __launch_bounds__(256) void k_accW(const float* __restrict__ xt,
                                              const float* __restrict__ sp,
                                              float* __restrict__ outt) {
    acc_body<false>(xt, sp, outt);
}

// ---------------------------------------------------------------------------
// Kernel 5: 1x1 conv, split-bf16 MFMA GEMM (M=12544, N=192, K=384) + BN + GELU.
// D = Ah*Bh + Al*Bh + Ah*Bl  (error ~2^-18 * sqrt(K) — fp32-grade).
// Tile 64x64, K-chunk 64, 4 waves (each 64m x 16n via 4 M-frags).
// ---------------------------------------------------------------------------
__global__ __launch_bounds__(256) void k_conv(const float* __restrict__ xt,
                                              const float* __restrict__ outt,
                                              const unsigned short* __restrict__ cwh,
                                              const unsigned short* __restrict__ cwl,
                                              const float* __restrict__ cb,
                                              const float* __restrict__ gma,
                                              const float* __restrict__ bta,
                                              const float* __restrict__ mea,
                                              const float* __restrict__ var,
                                              float* __restrict__ y) {
    __shared__ unsigned short AB[4 * 64 * 72];   // 36864 B; f32 D view fits too
    unsigned short* Ah = AB;
    unsigned short* Al = AB + 64 * 72;
    unsigned short* Bh = AB + 2 * 64 * 72;
    unsigned short* Bl = AB + 3 * 64 * 72;
    int bm = blockIdx.x * 64, bn = blockIdx.y * 64;
    int tid = threadIdx.x, lane = tid & 63, wv = tid >> 6;

    f32x4 acc[4] = {{0,0,0,0},{0,0,0,0},{0,0,0,0},{0,0,0,0}};

    for (int kc = 0; kc < 384; kc += 64) {
        const float* base = (kc < CC) ? xt : outt;
        int coff = (kc < CC) ? kc : kc - CC;
#pragma unroll
        for (int r2 = 0; r2 < 2; r2++) {
            int idx = tid + r2 * 256;
            int m = idx >> 3, kq = idx & 7;
            const float* s = base + (size_t)(bm + m) * CC + coff + kq * 8;
            float4 v0 = *(const float4*)s;
            float4 v1 = *(const float4*)(s + 4);
            float v[8] = {v0.x, v0.y, v0.z, v0.w, v1.x, v1.y, v1.z, v1.w};
            unsigned short hi[8], lo[8];
#pragma unroll
            for (int e = 0; e < 8; e++) {
                hi[e] = f2b(v[e]);
                lo[e] = f2b(v[e] - b2f(hi[e]));
            }
            *(short8*)&Ah[m * 72 + kq * 8] = *(short8*)hi;
            *(short8*)&Al[m * 72 + kq * 8] = *(short8*)lo;
            int n = m;   // Bs[n][k]; cwh/cwl are [o][c] = [n][k] (B^T layout)
            *(short8*)&Bh[n * 72 + kq * 8] =
                *(const short8*)(cwh + (size_t)(bn + n) * 384 + kc + kq * 8);
            *(short8*)&Bl[n * 72 + kq * 8] =
                *(const short8*)(cwl + (size_t)(bn + n) * 384 + kc + kq * 8);
        }
        __syncthreads();
        int n0 = wv * 16;
        int k8 = lane >> 4;        // 0..3
        int col = lane & 15;
#pragma unroll
        for (int ks = 0; ks < 64; ks += 32) {
            int koff = ks + k8 * 8;
            short8 bfh = *(const short8*)&Bh[(n0 + col) * 72 + koff];
            short8 bfl = *(const short8*)&Bl[(n0 + col) * 72 + koff];
#pragma unroll
            for (int fm = 0; fm < 4; fm++) {
                short8 afh = *(const short8*)&Ah[(fm * 16 + col) * 72 + koff];
                short8 afl = *(const short8*)&Al[(fm * 16 + col) * 72 + koff];
                acc[fm] = __builtin_amdgcn_mfma_f32_16x16x32_bf16(afh, bfh, acc[fm], 0, 0, 0);
                acc[fm] = __builtin_amdgcn_mfma_f32_16x16x32_bf16(afl, bfh, acc[fm], 0, 0, 0);
                acc[fm] = __builtin_amdgcn_mfma_f32_16x16x32_bf16(afh, bfl, acc[fm], 0, 0, 0);
            }
        }
        __syncthreads();
    }

    // Epilogue: LDS transpose for coalesced channel-major stores
    float* Ds = (float*)AB;
    {
        int col = lane & 15, rowq = lane >> 4;
#pragma unroll
        for (int fm = 0; fm < 4; fm++)
#pragma unroll
            for (int rg = 0; rg < 4; rg++)
                Ds[(fm * 16 + rowq * 4 + rg) * 68 + wv * 16 + col] = acc[fm][rg];
    }
    __syncthreads();
    {
        int o = tid >> 2, mq0 = tid & 3;
        int oo = bn + o;
        float bias = cb[oo];
        float inv  = gma[oo] * rsqrtf(var[oo] + 1e-5f);
        float mean = mea[oo], beta = bta[oo];
        int b = bm / HWW, p0 = bm % HWW;
#pragma unroll
        for (int g = 0; g < 4; g++) {
            int mq = mq0 + g * 4;
            float v[4];
#pragma unroll
            for (int j = 0; j < 4; j++) {
                float t = Ds[(mq * 4 + j) * 68 + o] + bias;
                t = (t - mean) * inv + beta;
                v[j] = 0.5f * t * (1.0f + erff(t * 0.70710678118654752f));
            }
            float4 st; st.x = v[0]; st.y = v[1]; st.z = v[2]; st.w = v[3];
            *(float4*)&y[(size_t)(b * CC + oo) * HWW + p0 + mq * 4] = st;
        }
    }
}

// ---------------------------------------------------------------------------
extern "C" void kernel_launch(void* const* d_in, const int* in_sizes, int n_in,
                              void* d_out, int out_size, void* d_ws, size_t ws_size,
                              hipStream_t stream) {
    const float* x   = (const float*)d_in[0];
    const float* cw  = (const float*)d_in[1];
    const float* cb  = (const float*)d_in[2];
    const float* gma = (const float*)d_in[3];
    const float* bta = (const float*)d_in[4];
    const float* mea = (const float*)d_in[5];
    const float* var = (const float*)d_in[6];
    float* out = (float*)d_out;

    float* ws = (float*)d_ws;
    float*          xt   = ws;                                  // 2,408,448 f32
    float*          sp   = ws + 2408448;                        //   677,376 f32
    float*          outt = ws + 3085824;                        // 2,408,448 f32
    unsigned short* cwh  = (unsigned short*)(ws + 5494272);     //    73,728 bf16
    unsigned short* cwl  = (unsigned short*)(ws + 5531136);     //    73,728 bf16

    k_transpose<<<dim3(98, 6, 4), dim3(32, 8), 0, stream>>>(x, xt);
    k_convw<<<288, 256, 0, stream>>>(cw, cwh, cwl);
    k_scores<<<896, 256, 0, stream>>>(xt, sp);
    k_accH<<<224, 256, 0, stream>>>(xt, sp, outt);
    k_accW<<<224, 256, 0, stream>>>(xt, sp, outt);
    k_conv<<<dim3(196, 3), 256, 0, stream>>>(xt, outt, cwh, cwl, cb, gma, bta, mea, var, out);
}